// Round 12
// baseline (216.723 us; speedup 1.0000x reference)
//
#include <hip/hip_runtime.h>

#define N_NODES 100000
#define N_EDGES 1000000
#define DEG_CAP 64
#define OVF_CAP 4096
#define SPILL_CAP 4096

// binning geometry
#define BKT_SH 8
#define BKT_NODES 256            // nodes per bucket
#define NBKT 392                 // 392*256 = 100352 >= N_NODES
#define BKT_CAP 4096             // record capacity per bucket (mean ~2551)
#define BIN_CHUNK 4096           // edges per bin block
#define FIFO_CAP 32              // LDS fifo depth per bucket (mean ~10.4)

typedef __attribute__((ext_vector_type(8))) short bf16x8;
typedef __attribute__((ext_vector_type(4))) float f32x4;

__device__ __forceinline__ unsigned short f2bf(float f) {
    unsigned u = __float_as_uint(f);
    return (unsigned short)((u + 0x7FFF + ((u >> 16) & 1)) >> 16);
}
__device__ __forceinline__ float bf2f(unsigned short b) {
    return __uint_as_float(((unsigned)b) << 16);
}
__device__ __forceinline__ float bflo(unsigned u) {   // low bf16 of a dword
    return __uint_as_float(u << 16);
}
__device__ __forceinline__ float bfhi(unsigned u) {   // high bf16 of a dword
    return __uint_as_float(u & 0xffff0000u);
}
// rounded hi + rounded residual lo: hi is BIT-IDENTICAL to f2bf(f) (the
// gather source), and hi+lo reconstructs f to ~2^-17 relative.
__device__ __forceinline__ void split_rbf(float f, unsigned short& ho,
                                          unsigned short& lo) {
    unsigned short hb = f2bf(f);
    ho = hb;
    lo = f2bf(f - bf2f(hb));
}

// ws layout (4B units) — AUDITED (u16 plane = N*64 u16 = 3,200,000 dwords):
//   counts : [0, 100352)
//   ovfc 100352 ; spillc 100353
//   gcur   : [100416, 100928)
//   ovf    : [100928, 109120)
//   spill  : [109120, 117312)
//   Bf1    : s16 [117312, 133696)
//   Bf2    : s16 [133696, 150080)
//   slots  : [150080, 6572608)        100352*64 dwords
//   rec    : u32 [6572608, 8178240)   392*4096
//   xh     : u16 [8178240,  11378240) 3.2M dwords = 6.4M u16
//   xl     : u16 [11378240, 14578240)
//   mh     : u16 [14578240, 17778240)
//   ml     : u16 [17778240, 20978240)
//   p_bf   : u16 [20978240, 24178240)
//   q      : f32 [24178240, 30578240)
// total 30,578,240 dwords = 122.3 MB

// Merged init + weight-split + x -> rounded-hi/residual-lo planes.
__global__ __launch_bounds__(256) void prep_kernel(
        const float4* __restrict__ x4,
        ushort4* __restrict__ xh4, ushort4* __restrict__ xl4,
        const float* __restrict__ W1l, const float* __restrict__ W1r,
        const float* __restrict__ W2l, const float* __restrict__ W2r,
        short* __restrict__ Bf1, short* __restrict__ Bf2,
        int4* __restrict__ gcur4, int* __restrict__ ovfc,
        int* __restrict__ spillc) {
    int i = blockIdx.x * blockDim.x + threadIdx.x;
    if (i < 128) gcur4[i] = make_int4(0, 0, 0, 0);
    if (i == 0) { *ovfc = 0; *spillc = 0; }
    if (i < 32768) {
        int g = i >> 14;
        int e = i & 16383;
        int k = e >> 7;
        int n = e & 127;
        float v;
        if (g == 0) v = (k < 64) ? W1l[k * 128 + n] : W1r[(k - 64) * 128 + n];
        else        v = (n < 64) ? W2l[k * 64 + n]  : W2r[k * 64 + (n - 64)];
        unsigned short hb, lb;
        split_rbf(v, hb, lb);
        int c = n >> 4, kc = k >> 5;
        int lane = (((k >> 3) & 3) << 4) | (n & 15);
        int j = k & 7;
        short* base = g ? Bf2 : Bf1;
        base[((c * 4 + kc) * 2 + 0) * 512 + lane * 8 + j] = (short)hb;
        base[((c * 4 + kc) * 2 + 1) * 512 + lane * 8 + j] = (short)lb;
    }
    if (i < N_NODES * 16) {
        float4 v = x4[i];
        ushort4 oh, ol;
        split_rbf(v.x, oh.x, ol.x);
        split_rbf(v.y, oh.y, ol.y);
        split_rbf(v.z, oh.z, ol.z);
        split_rbf(v.w, oh.w, ol.w);
        xh4[i] = oh;
        xl4[i] = ol;
    }
}

// Pass A: bin edges into 392 dst-range buckets via LDS FIFOs.
__global__ __launch_bounds__(256) void bin_kernel(
        const int* __restrict__ ei, unsigned* __restrict__ rec,
        int* __restrict__ gcur, int* __restrict__ spillc,
        int2* __restrict__ spill) {
    __shared__ int lcnt[NBKT];
    __shared__ unsigned fifo[NBKT * FIFO_CAP];   // 50KB
    for (int i = threadIdx.x; i < NBKT; i += 256) lcnt[i] = 0;
    __syncthreads();
    int base = blockIdx.x * BIN_CHUNK;
    int end = base + BIN_CHUNK;
    if (end > N_EDGES) end = N_EDGES;
    for (int e = base + threadIdx.x; e < end; e += 256) {
        int s = ei[e];
        int d = ei[N_EDGES + e];
        int b = d >> BKT_SH;
        unsigned r = ((unsigned)s << BKT_SH) | (unsigned)(d & (BKT_NODES - 1));
        int pos = atomicAdd(&lcnt[b], 1);
        if (pos < FIFO_CAP) {
            fifo[b * FIFO_CAP + pos] = r;
        } else {
            int o = atomicAdd(spillc, 1);
            if (o < SPILL_CAP) spill[o] = make_int2(s, d);
        }
    }
    __syncthreads();
    for (int b = threadIdx.x; b < NBKT; b += 256) {
        int cnt = lcnt[b];
        if (cnt > FIFO_CAP) cnt = FIFO_CAP;
        if (cnt == 0) continue;
        int gb = atomicAdd(&gcur[b], cnt);
        for (int k = 0; k < cnt; ++k) {
            int g = gb + k;
            unsigned r = fifo[b * FIFO_CAP + k];
            if (g < BKT_CAP) {
                rec[b * BKT_CAP + g] = r;
            } else {
                int o = atomicAdd(spillc, 1);
                if (o < SPILL_CAP)
                    spill[o] = make_int2((int)(r >> BKT_SH),
                                         (b << BKT_SH) | (int)(r & (BKT_NODES - 1)));
            }
        }
    }
}

// Pass B: one block per bucket; counts + slots tile built in LDS (65KB),
// written out fully coalesced. Spill entries handled inline.
__global__ __launch_bounds__(256) void build_kernel(
        const unsigned* __restrict__ rec, const int* __restrict__ gcur,
        const int2* __restrict__ spill, const int* __restrict__ spillc,
        int* __restrict__ counts, int* __restrict__ slots,
        int* __restrict__ ovfc, int* __restrict__ ovf) {
    __shared__ int lcnt[BKT_NODES];
    __shared__ int lslots[BKT_NODES * DEG_CAP];   // 64KB
    int b = blockIdx.x;
    for (int i = threadIdx.x; i < BKT_NODES; i += 256) lcnt[i] = 0;
    __syncthreads();
    int n = gcur[b];
    if (n > BKT_CAP) n = BKT_CAP;
    for (int i = threadIdx.x; i < n; i += 256) {
        unsigned r = rec[b * BKT_CAP + i];
        int dlo = (int)(r & (BKT_NODES - 1));
        int src = (int)(r >> BKT_SH);
        int pos = atomicAdd(&lcnt[dlo], 1);
        if (pos < DEG_CAP) {
            lslots[dlo * DEG_CAP + pos] = src;
        } else {
            int o = atomicAdd(ovfc, 1);
            if (o < OVF_CAP) {
                ovf[o * 2] = src;
                ovf[o * 2 + 1] = (b << BKT_SH) | dlo;
            }
        }
    }
    // inline spill handling (usually ns == 0)
    int ns = *spillc;
    if (ns > SPILL_CAP) ns = SPILL_CAP;
    for (int i = threadIdx.x; i < ns; i += 256) {
        int2 e = spill[i];
        if ((e.y >> BKT_SH) == b) {
            int dlo = e.y & (BKT_NODES - 1);
            int pos = atomicAdd(&lcnt[dlo], 1);
            if (pos < DEG_CAP) {
                lslots[dlo * DEG_CAP + pos] = e.x;
            } else {
                int o = atomicAdd(ovfc, 1);
                if (o < OVF_CAP) { ovf[o * 2] = e.x; ovf[o * 2 + 1] = e.y; }
            }
        }
    }
    __syncthreads();
    int nodeBase = b << BKT_SH;
    for (int i = threadIdx.x; i < BKT_NODES; i += 256)
        counts[nodeBase + i] = lcnt[i];
    const int4* ls4 = (const int4*)lslots;
    int4* gs4 = (int4*)(slots + nodeBase * DEG_CAP);
    for (int i = threadIdx.x; i < BKT_NODES * DEG_CAP / 4; i += 256)
        gs4[i] = ls4[i];
}

// Layer-1 gather, 16-lane-group-per-node (16 nodes/block), 4-wide unroll
// for memory-level parallelism (verified: -37us vs wave-per-node).
__global__ __launch_bounds__(256) void gather_bf_kernel(
        const unsigned short* __restrict__ feat, const int* __restrict__ counts,
        const int* __restrict__ slots,
        unsigned short* __restrict__ mh, unsigned short* __restrict__ ml) {
    int node = blockIdx.x * 16 + (threadIdx.x >> 4);
    int t = threadIdx.x & 15;
    if (node >= N_NODES) return;
    int deg = counts[node];
    int dcap = min(deg, DEG_CAP);
    const int gbase = threadIdx.x & 48;   // group's lane base within wave
    float a0 = 0.f, a1 = 0.f, a2 = 0.f, a3 = 0.f;
    for (int phase = 0; phase * 16 < dcap; ++phase) {
        int ids16 = slots[node * DEG_CAP + phase * 16 + t];
        int lim = min(dcap - phase * 16, 16);
        int j = 0;
        for (; j + 4 <= lim; j += 4) {
            int s0 = __shfl(ids16, gbase | (j + 0));
            int s1 = __shfl(ids16, gbase | (j + 1));
            int s2 = __shfl(ids16, gbase | (j + 2));
            int s3 = __shfl(ids16, gbase | (j + 3));
            uint2 u0 = *(const uint2*)(feat + s0 * 64 + t * 4);
            uint2 u1 = *(const uint2*)(feat + s1 * 64 + t * 4);
            uint2 u2 = *(const uint2*)(feat + s2 * 64 + t * 4);
            uint2 u3 = *(const uint2*)(feat + s3 * 64 + t * 4);
            a0 += bflo(u0.x) + bflo(u1.x) + bflo(u2.x) + bflo(u3.x);
            a1 += bfhi(u0.x) + bfhi(u1.x) + bfhi(u2.x) + bfhi(u3.x);
            a2 += bflo(u0.y) + bflo(u1.y) + bflo(u2.y) + bflo(u3.y);
            a3 += bfhi(u0.y) + bfhi(u1.y) + bfhi(u2.y) + bfhi(u3.y);
        }
        for (; j < lim; ++j) {
            int s = __shfl(ids16, gbase | j);
            uint2 u = *(const uint2*)(feat + s * 64 + t * 4);
            a0 += bflo(u.x);
            a1 += bfhi(u.x);
            a2 += bflo(u.y);
            a3 += bfhi(u.y);
        }
    }
    float inv = 1.0f / fmaxf((float)deg, 1.0f);
    ushort4 oh, ol;
    split_rbf(a0 * inv, oh.x, ol.x);
    split_rbf(a1 * inv, oh.y, ol.y);
    split_rbf(a2 * inv, oh.z, ol.z);
    split_rbf(a3 * inv, oh.w, ol.w);
    *(ushort4*)&mh[node * 64 + t * 4] = oh;
    *(ushort4*)&ml[node * 64 + t * 4] = ol;
}

// A-fragment loader for mlp phase 1 (hi/lo planes, zero beyond N).
__device__ __forceinline__ void load_afrags(
        int row, bool rv,
        const unsigned short* __restrict__ mh, const unsigned short* __restrict__ ml,
        const unsigned short* __restrict__ xh, const unsigned short* __restrict__ xl,
        int quad, bf16x8 ah[4], bf16x8 al[4]) {
    const bf16x8 zz = {0, 0, 0, 0, 0, 0, 0, 0};
#pragma unroll
    for (int kc = 0; kc < 4; ++kc) {
        if (rv) {
            const int off = row * 64 + (kc & 1) * 32 + quad * 8;
            const unsigned short* ph = (kc < 2) ? (mh + off) : (xh + off);
            const unsigned short* pl = (kc < 2) ? (ml + off) : (xl + off);
            ah[kc] = *(const bf16x8*)ph;
            al[kc] = *(const bf16x8*)(pl);
        } else {
            ah[kc] = zz;
            al[kc] = zz;
        }
    }
}

// FUSED MLP, 128-row tiles, 4 waves × 2 col-tiles (measured optimum).
// Phase 1 is EXPLICITLY software-pipelined: double-buffered A-fragment
// sets, prefetch of row-tile rt+1 issued before rt's MFMA cluster. The
// kernel is latency-bound (2us MFMA floor, 10us HBM floor, ran 48-71us);
// round-11 showed the compiler's implicit load clustering is fragile
// under co-compilation (identical source: 47.8 -> 71.4us, same FETCH,
// same MFMA cycles, +50% stalls). This pins >=8 loads in flight.
__global__ __launch_bounds__(256) void mlp_fused_kernel(
        const unsigned short* __restrict__ mh, const unsigned short* __restrict__ ml,
        const unsigned short* __restrict__ xh, const unsigned short* __restrict__ xl,
        const float* __restrict__ x,
        const short* __restrict__ Bf1, const float* __restrict__ b1,
        const short* __restrict__ Bf2, const float* __restrict__ b2,
        const int* __restrict__ ovf, const int* __restrict__ ovfc,
        const int* __restrict__ counts,
        unsigned short* __restrict__ p_bf_out, float* __restrict__ q) {
    __shared__ unsigned short h_lds[128][136];   // 34816 B
    const int w = threadIdx.x >> 6;
    const int l = threadIdx.x & 63;
    const int lane15 = l & 15;
    const int quad = l >> 4;
    const int rowBase = blockIdx.x * 128;

    // ---- preamble: layer-1 overflow fix for this block's rows ----
    {
        int n = *ovfc;
        if (n > OVF_CAP) n = OVF_CAP;
        if (n > 0) {
            for (int idx = 0; idx < n; ++idx) {
                int d = ovf[idx * 2 + 1];
                if (d >= rowBase && d < rowBase + 128) {
                    if (threadIdx.x < 64) {
                        int s = ovf[idx * 2];
                        int t = threadIdx.x;
                        float inv = 1.0f / fmaxf((float)counts[d], 1.0f);
                        float m = bf2f(mh[d * 64 + t]) + bf2f(ml[d * 64 + t])
                                + x[s * 64 + t] * inv;
                        unsigned short hb, lb;
                        split_rbf(m, hb, lb);
                        ((unsigned short*)mh)[d * 64 + t] = hb;
                        ((unsigned short*)ml)[d * 64 + t] = lb;
                    }
                    __syncthreads();
                }
            }
            __syncthreads();
        }
    }

    // ---- phase 1: layer 1, B-stationary, 3-MFMA hi/lo split,
    //      2-stage software pipeline on A-fragments ----
    {
        bf16x8 bh[2][4], bl[2][4];
#pragma unroll
        for (int ci = 0; ci < 2; ++ci) {
            const int c = 2 * w + ci;
#pragma unroll
            for (int kc = 0; kc < 4; ++kc) {
                const short* bp = Bf1 + ((c * 4 + kc) * 2) * 512 + l * 8;
                bh[ci][kc] = *(const bf16x8*)bp;
                bl[ci][kc] = *(const bf16x8*)(bp + 512);
            }
        }
        float bias[2];
#pragma unroll
        for (int ci = 0; ci < 2; ++ci) bias[ci] = b1[(2 * w + ci) * 16 + lane15];

        auto compute_store = [&](bf16x8 (&ah)[4], bf16x8 (&al)[4], int rt) {
            f32x4 acc[2] = {(f32x4){0.f, 0.f, 0.f, 0.f},
                            (f32x4){0.f, 0.f, 0.f, 0.f}};
#pragma unroll
            for (int kc = 0; kc < 4; ++kc) {
#pragma unroll
                for (int ci = 0; ci < 2; ++ci) {
                    acc[ci] = __builtin_amdgcn_mfma_f32_16x16x32_bf16(ah[kc], bh[ci][kc], acc[ci], 0, 0, 0);
                    acc[ci] = __builtin_amdgcn_mfma_f32_16x16x32_bf16(al[kc], bh[ci][kc], acc[ci], 0, 0, 0);
                    acc[ci] = __builtin_amdgcn_mfma_f32_16x16x32_bf16(ah[kc], bl[ci][kc], acc[ci], 0, 0, 0);
                }
            }
            const int rloc = rt * 16 + quad * 4;
#pragma unroll
            for (int ci = 0; ci < 2; ++ci) {
                const int col = (2 * w + ci) * 16 + lane15;
#pragma unroll
                for (int i = 0; i < 4; ++i)
                    h_lds[rloc + i][col] =
                        f2bf(fmaxf(acc[ci][i] + bias[ci], 0.f));
            }
        };

        bf16x8 ahA[4], alA[4], ahB[4], alB[4];
        {
            const int r0 = rowBase + lane15;
            load_afrags(r0, r0 < N_NODES, mh, ml, xh, xl, quad, ahA, alA);
        }
#pragma unroll
        for (int rt = 0; rt < 8; rt += 2) {
            {   // prefetch rt+1 into B before computing rt
                const int rB = rowBase + (rt + 1) * 16 + lane15;
                load_afrags(rB, rB < N_NODES, mh, ml, xh, xl, quad, ahB, alB);
            }
            compute_store(ahA, alA, rt);
            if (rt + 2 < 8) {   // prefetch rt+2 into A before computing rt+1
                const int rA = rowBase + (rt + 2) * 16 + lane15;
                load_afrags(rA, rA < N_NODES, mh, ml, xh, xl, quad, ahA, alA);
            }
            compute_store(ahB, alB, rt + 1);
        }
    }
    __syncthreads();

    // ---- phase 2: layer 2 from LDS (A = bf16, W2 keeps hi/lo split) ----
    {
        bf16x8 bh[2][4], bl[2][4];
#pragma unroll
        for (int ci = 0; ci < 2; ++ci) {
            const int c = 2 * w + ci;
#pragma unroll
            for (int kc = 0; kc < 4; ++kc) {
                const short* bp = Bf2 + ((c * 4 + kc) * 2) * 512 + l * 8;
                bh[ci][kc] = *(const bf16x8*)bp;
                bl[ci][kc] = *(const bf16x8*)(bp + 512);
            }
        }
        float bias[2];
#pragma unroll
        for (int ci = 0; ci < 2; ++ci) {
            const int c = 2 * w + ci;
            bias[ci] = (c >= 4) ? b2[(c - 4) * 16 + lane15] : 0.f;
        }

#pragma unroll
        for (int rt = 0; rt < 8; ++rt) {
            bf16x8 ah[4];
#pragma unroll
            for (int kc = 0; kc < 4; ++kc)
                ah[kc] = *(const bf16x8*)&h_lds[rt * 16 + lane15][kc * 32 + quad * 8];

            f32x4 acc[2] = {(f32x4){0.f, 0.f, 0.f, 0.f}, (f32x4){0.f, 0.f, 0.f, 0.f}};
#pragma unroll
            for (int kc = 0; kc < 4; ++kc) {
#pragma unroll
                for (int ci = 0; ci < 2; ++ci) {
                    acc[ci] = __builtin_amdgcn_mfma_f32_16x16x32_bf16(ah[kc], bh[ci][kc], acc[ci], 0, 0, 0);
                    acc[ci] = __builtin_amdgcn_mfma_f32_16x16x32_bf16(ah[kc], bl[ci][kc], acc[ci], 0, 0, 0);
                }
            }

            const int rb = rowBase + rt * 16 + quad * 4;
#pragma unroll
            for (int ci = 0; ci < 2; ++ci) {
                const int c = 2 * w + ci;
                if (c < 4) {
#pragma unroll
                    for (int i = 0; i < 4; ++i) {
                        int r = rb + i;
                        if (r < N_NODES)
                            p_bf_out[r * 64 + c * 16 + lane15] = f2bf(acc[ci][i]);
                    }
                } else {
#pragma unroll
                    for (int i = 0; i < 4; ++i) {
                        int r = rb + i;
                        if (r < N_NODES)
                            q[r * 64 + (c - 4) * 16 + lane15] = acc[ci][i] + bias[ci];
                    }
                }
            }
        }
    }
}

// Layer-2 gather + epilogue, 16-lane-group-per-node.
// out = mean(p_bf[nbrs]) + q, ovf added inline.
__global__ __launch_bounds__(256) void gather_final_kernel(
        const unsigned short* __restrict__ p, const int* __restrict__ counts,
        const int* __restrict__ slots, const float* __restrict__ q,
        const int* __restrict__ ovf, const int* __restrict__ ovfc,
        float* __restrict__ out) {
    int node = blockIdx.x * 16 + (threadIdx.x >> 4);
    int t = threadIdx.x & 15;
    if (node >= N_NODES) return;
    int deg = counts[node];
    int dcap = min(deg, DEG_CAP);
    const int gbase = threadIdx.x & 48;
    float a0 = 0.f, a1 = 0.f, a2 = 0.f, a3 = 0.f;
    for (int phase = 0; phase * 16 < dcap; ++phase) {
        int ids16 = slots[node * DEG_CAP + phase * 16 + t];
        int lim = min(dcap - phase * 16, 16);
        int j = 0;
        for (; j + 4 <= lim; j += 4) {
            int s0 = __shfl(ids16, gbase | (j + 0));
            int s1 = __shfl(ids16, gbase | (j + 1));
            int s2 = __shfl(ids16, gbase | (j + 2));
            int s3 = __shfl(ids16, gbase | (j + 3));
            uint2 u0 = *(const uint2*)(p + s0 * 64 + t * 4);
            uint2 u1 = *(const uint2*)(p + s1 * 64 + t * 4);
            uint2 u2 = *(const uint2*)(p + s2 * 64 + t * 4);
            uint2 u3 = *(const uint2*)(p + s3 * 64 + t * 4);
            a0 += bflo(u0.x) + bflo(u1.x) + bflo(u2.x) + bflo(u3.x);
            a1 += bfhi(u0.x) + bfhi(u1.x) + bfhi(u2.x) + bfhi(u3.x);
            a2 += bflo(u0.y) + bflo(u1.y) + bflo(u2.y) + bflo(u3.y);
            a3 += bfhi(u0.y) + bfhi(u1.y) + bfhi(u2.y) + bfhi(u3.y);
        }
        for (; j < lim; ++j) {
            int s = __shfl(ids16, gbase | j);
            uint2 u = *(const uint2*)(p + s * 64 + t * 4);
            a0 += bflo(u.x);
            a1 += bfhi(u.x);
            a2 += bflo(u.y);
            a3 += bfhi(u.y);
        }
    }
    // inline layer-2 overflow additions (n is ~always 0)
    int n = *ovfc;
    if (n > OVF_CAP) n = OVF_CAP;
    for (int idx = 0; idx < n; ++idx) {
        if (ovf[idx * 2 + 1] == node) {
            int s = ovf[idx * 2];
            uint2 u = *(const uint2*)(p + s * 64 + t * 4);
            a0 += bflo(u.x);
            a1 += bfhi(u.x);
            a2 += bflo(u.y);
            a3 += bfhi(u.y);
        }
    }
    float inv = 1.0f / fmaxf((float)deg, 1.0f);
    float4 qv = *(const float4*)&q[node * 64 + t * 4];
    *(float4*)&out[node * 64 + t * 4] =
        make_float4(a0 * inv + qv.x, a1 * inv + qv.y,
                    a2 * inv + qv.z, a3 * inv + qv.w);
}

extern "C" void kernel_launch(void* const* d_in, const int* in_sizes, int n_in,
                              void* d_out, int out_size, void* d_ws, size_t ws_size,
                              hipStream_t stream) {
    const float* x   = (const float*)d_in[0];
    const float* W1l = (const float*)d_in[1];
    const float* W1r = (const float*)d_in[2];
    const float* b1  = (const float*)d_in[3];
    const float* W2l = (const float*)d_in[4];
    const float* W2r = (const float*)d_in[5];
    const float* b2  = (const float*)d_in[6];
    const int*   ei  = (const int*)d_in[7];

    int*   wsi      = (int*)d_ws;
    float* wsf      = (float*)d_ws;
    int*   counts   = wsi;
    int*   ovfc     = wsi + 100352;
    int*   spillc   = wsi + 100353;
    int*   gcur     = wsi + 100416;
    int*   ovf      = wsi + 100928;
    int2*  spill    = (int2*)(wsi + 109120);
    short* Bf1      = (short*)(wsi + 117312);
    short* Bf2      = (short*)(wsi + 133696);
    int*   slots    = wsi + 150080;
    unsigned* rec   = (unsigned*)(wsi + 6572608);
    unsigned short* xh = (unsigned short*)(wsi + 8178240);
    unsigned short* xl = (unsigned short*)(wsi + 11378240);
    unsigned short* mh = (unsigned short*)(wsi + 14578240);
    unsigned short* ml = (unsigned short*)(wsi + 17778240);
    unsigned short* p_bf = (unsigned short*)(wsi + 20978240);
    float* q        = wsf + 24178240;
    float* out      = (float*)d_out;

    prep_kernel<<<(N_NODES * 16 + 255) / 256, 256, 0, stream>>>(
        (const float4*)x, (ushort4*)xh, (ushort4*)xl, W1l, W1r, W2l, W2r,
        Bf1, Bf2, (int4*)gcur, ovfc, spillc);

    // indexing: LDS-binned two-pass (spill handled inside build)
    bin_kernel<<<(N_EDGES + BIN_CHUNK - 1) / BIN_CHUNK, 256, 0, stream>>>(
        ei, rec, gcur, spillc, spill);
    build_kernel<<<NBKT, 256, 0, stream>>>(
        rec, gcur, spill, spillc, counts, slots, ovfc, ovf);

    // layer-1 aggregation -> mean hi/lo planes (16 nodes/block)
    gather_bf_kernel<<<(N_NODES + 15) / 16, 256, 0, stream>>>(
        xh, counts, slots, mh, ml);

    // fused MLP (ovf preamble inside): h (LDS) -> p_bf, q
    mlp_fused_kernel<<<(N_NODES + 127) / 128, 256, 0, stream>>>(
        mh, ml, xh, xl, x, Bf1, b1, Bf2, b2, ovf, ovfc, counts, p_bf, q);

    // fused layer-2 aggregation + epilogue (ovf additions inside)
    gather_final_kernel<<<(N_NODES + 15) / 16, 256, 0, stream>>>(
        p_bf, counts, slots, q, ovf, ovfc, out);
}

// Round 13
// 212.604 us; speedup vs baseline: 1.0194x; 1.0194x over previous
//
#include <hip/hip_runtime.h>

#define N_NODES 100000
#define N_EDGES 1000000
#define DEG_CAP 64
#define OVF_CAP 4096
#define SPILL_CAP 4096

// binning geometry
#define BKT_SH 8
#define BKT_NODES 256            // nodes per bucket
#define NBKT 392                 // 392*256 = 100352 >= N_NODES
#define BKT_CAP 4096             // record capacity per bucket (mean ~2551)
#define BIN_CHUNK 4096           // edges per bin block
#define FIFO_CAP 32              // LDS fifo depth per bucket (mean ~10.4)

typedef __attribute__((ext_vector_type(8))) short bf16x8;
typedef __attribute__((ext_vector_type(4))) float f32x4;

__device__ __forceinline__ unsigned short f2bf(float f) {
    unsigned u = __float_as_uint(f);
    return (unsigned short)((u + 0x7FFF + ((u >> 16) & 1)) >> 16);
}
__device__ __forceinline__ float bf2f(unsigned short b) {
    return __uint_as_float(((unsigned)b) << 16);
}
__device__ __forceinline__ float bflo(unsigned u) {   // low bf16 of a dword
    return __uint_as_float(u << 16);
}
__device__ __forceinline__ float bfhi(unsigned u) {   // high bf16 of a dword
    return __uint_as_float(u & 0xffff0000u);
}
// rounded hi + rounded residual lo: hi is BIT-IDENTICAL to f2bf(f) (the
// gather source), and hi+lo reconstructs f to ~2^-17 relative.
__device__ __forceinline__ void split_rbf(float f, unsigned short& ho,
                                          unsigned short& lo) {
    unsigned short hb = f2bf(f);
    ho = hb;
    lo = f2bf(f - bf2f(hb));
}

// ws layout (4B units) — AUDITED (u16 plane = N*64 u16 = 3,200,000 dwords):
//   counts : [0, 100352)
//   ovfc 100352 ; spillc 100353
//   gcur   : [100416, 100928)
//   ovf    : [100928, 109120)
//   spill  : [109120, 117312)
//   Bf1    : s16 [117312, 133696)
//   Bf2    : s16 [133696, 150080)
//   slots  : [150080, 6572608)        100352*64 dwords
//   rec    : u32 [6572608, 8178240)   392*4096
//   xh     : u16 [8178240,  11378240) 3.2M dwords = 6.4M u16
//   xl     : u16 [11378240, 14578240)
//   (mh/ml regions now unused — gather fused into mlp)
//   p_bf   : u16 [20978240, 24178240)
//   q      : f32 [24178240, 30578240)
// total 30,578,240 dwords = 122.3 MB

// Merged init + weight-split + x -> rounded-hi/residual-lo planes.
__global__ __launch_bounds__(256) void prep_kernel(
        const float4* __restrict__ x4,
        ushort4* __restrict__ xh4, ushort4* __restrict__ xl4,
        const float* __restrict__ W1l, const float* __restrict__ W1r,
        const float* __restrict__ W2l, const float* __restrict__ W2r,
        short* __restrict__ Bf1, short* __restrict__ Bf2,
        int4* __restrict__ gcur4, int* __restrict__ ovfc,
        int* __restrict__ spillc) {
    int i = blockIdx.x * blockDim.x + threadIdx.x;
    if (i < 128) gcur4[i] = make_int4(0, 0, 0, 0);
    if (i == 0) { *ovfc = 0; *spillc = 0; }
    if (i < 32768) {
        int g = i >> 14;
        int e = i & 16383;
        int k = e >> 7;
        int n = e & 127;
        float v;
        if (g == 0) v = (k < 64) ? W1l[k * 128 + n] : W1r[(k - 64) * 128 + n];
        else        v = (n < 64) ? W2l[k * 64 + n]  : W2r[k * 64 + (n - 64)];
        unsigned short hb, lb;
        split_rbf(v, hb, lb);
        int c = n >> 4, kc = k >> 5;
        int lane = (((k >> 3) & 3) << 4) | (n & 15);
        int j = k & 7;
        short* base = g ? Bf2 : Bf1;
        base[((c * 4 + kc) * 2 + 0) * 512 + lane * 8 + j] = (short)hb;
        base[((c * 4 + kc) * 2 + 1) * 512 + lane * 8 + j] = (short)lb;
    }
    if (i < N_NODES * 16) {
        float4 v = x4[i];
        ushort4 oh, ol;
        split_rbf(v.x, oh.x, ol.x);
        split_rbf(v.y, oh.y, ol.y);
        split_rbf(v.z, oh.z, ol.z);
        split_rbf(v.w, oh.w, ol.w);
        xh4[i] = oh;
        xl4[i] = ol;
    }
}

// Pass A: bin edges into 392 dst-range buckets via LDS FIFOs.
__global__ __launch_bounds__(256) void bin_kernel(
        const int* __restrict__ ei, unsigned* __restrict__ rec,
        int* __restrict__ gcur, int* __restrict__ spillc,
        int2* __restrict__ spill) {
    __shared__ int lcnt[NBKT];
    __shared__ unsigned fifo[NBKT * FIFO_CAP];   // 50KB
    for (int i = threadIdx.x; i < NBKT; i += 256) lcnt[i] = 0;
    __syncthreads();
    int base = blockIdx.x * BIN_CHUNK;
    int end = base + BIN_CHUNK;
    if (end > N_EDGES) end = N_EDGES;
    for (int e = base + threadIdx.x; e < end; e += 256) {
        int s = ei[e];
        int d = ei[N_EDGES + e];
        int b = d >> BKT_SH;
        unsigned r = ((unsigned)s << BKT_SH) | (unsigned)(d & (BKT_NODES - 1));
        int pos = atomicAdd(&lcnt[b], 1);
        if (pos < FIFO_CAP) {
            fifo[b * FIFO_CAP + pos] = r;
        } else {
            int o = atomicAdd(spillc, 1);
            if (o < SPILL_CAP) spill[o] = make_int2(s, d);
        }
    }
    __syncthreads();
    for (int b = threadIdx.x; b < NBKT; b += 256) {
        int cnt = lcnt[b];
        if (cnt > FIFO_CAP) cnt = FIFO_CAP;
        if (cnt == 0) continue;
        int gb = atomicAdd(&gcur[b], cnt);
        for (int k = 0; k < cnt; ++k) {
            int g = gb + k;
            unsigned r = fifo[b * FIFO_CAP + k];
            if (g < BKT_CAP) {
                rec[b * BKT_CAP + g] = r;
            } else {
                int o = atomicAdd(spillc, 1);
                if (o < SPILL_CAP)
                    spill[o] = make_int2((int)(r >> BKT_SH),
                                         (b << BKT_SH) | (int)(r & (BKT_NODES - 1)));
            }
        }
    }
}

// Pass B: one block per bucket; counts + slots tile built in LDS (65KB),
// written out fully coalesced. Spill entries handled inline.
__global__ __launch_bounds__(256) void build_kernel(
        const unsigned* __restrict__ rec, const int* __restrict__ gcur,
        const int2* __restrict__ spill, const int* __restrict__ spillc,
        int* __restrict__ counts, int* __restrict__ slots,
        int* __restrict__ ovfc, int* __restrict__ ovf) {
    __shared__ int lcnt[BKT_NODES];
    __shared__ int lslots[BKT_NODES * DEG_CAP];   // 64KB
    int b = blockIdx.x;
    for (int i = threadIdx.x; i < BKT_NODES; i += 256) lcnt[i] = 0;
    __syncthreads();
    int n = gcur[b];
    if (n > BKT_CAP) n = BKT_CAP;
    for (int i = threadIdx.x; i < n; i += 256) {
        unsigned r = rec[b * BKT_CAP + i];
        int dlo = (int)(r & (BKT_NODES - 1));
        int src = (int)(r >> BKT_SH);
        int pos = atomicAdd(&lcnt[dlo], 1);
        if (pos < DEG_CAP) {
            lslots[dlo * DEG_CAP + pos] = src;
        } else {
            int o = atomicAdd(ovfc, 1);
            if (o < OVF_CAP) {
                ovf[o * 2] = src;
                ovf[o * 2 + 1] = (b << BKT_SH) | dlo;
            }
        }
    }
    // inline spill handling (usually ns == 0)
    int ns = *spillc;
    if (ns > SPILL_CAP) ns = SPILL_CAP;
    for (int i = threadIdx.x; i < ns; i += 256) {
        int2 e = spill[i];
        if ((e.y >> BKT_SH) == b) {
            int dlo = e.y & (BKT_NODES - 1);
            int pos = atomicAdd(&lcnt[dlo], 1);
            if (pos < DEG_CAP) {
                lslots[dlo * DEG_CAP + pos] = e.x;
            } else {
                int o = atomicAdd(ovfc, 1);
                if (o < OVF_CAP) { ovf[o * 2] = e.x; ovf[o * 2 + 1] = e.y; }
            }
        }
    }
    __syncthreads();
    int nodeBase = b << BKT_SH;
    for (int i = threadIdx.x; i < BKT_NODES; i += 256)
        counts[nodeBase + i] = lcnt[i];
    const int4* ls4 = (const int4*)lslots;
    int4* gs4 = (int4*)(slots + nodeBase * DEG_CAP);
    for (int i = threadIdx.x; i < BKT_NODES * DEG_CAP / 4; i += 256)
        gs4[i] = ls4[i];
}

// FUSED gather + MLP, 128-row tiles, 4 waves × 2 col-tiles.
// Phase 0: wave w gathers means for local rows [w*32, w*32+32): lane =
// (row-in-16, feature-octet-pair). Per neighbor: two independent 16B xh
// loads per lane; fp32 accumulate; ovf entries (deg>64) folded in; split
// to hi/lo planes in LDS. The gather's random-access latency overlaps
// with OTHER blocks' MFMA phases on the same CU (2 blocks/CU).
// Deletes: gather_bf launch, mh/ml global planes (25.6MB round trip),
// ovf-preamble global RMW.
// Phase 1: A mean-frags from LDS, x-frags double-buffered from global.
// Phase 2: layer 2 from h_lds as before.
__global__ __launch_bounds__(256) void mlp_fused_kernel(
        const unsigned short* __restrict__ xh, const unsigned short* __restrict__ xl,
        const float* __restrict__ x,
        const int* __restrict__ counts, const int* __restrict__ slots,
        const short* __restrict__ Bf1, const float* __restrict__ b1,
        const short* __restrict__ Bf2, const float* __restrict__ b2,
        const int* __restrict__ ovf, const int* __restrict__ ovfc,
        unsigned short* __restrict__ p_bf_out, float* __restrict__ q) {
    __shared__ unsigned short mean_h[128][72];   // 18432 B (144B row stride)
    __shared__ unsigned short mean_l[128][72];   // 18432 B
    __shared__ unsigned short h_lds[128][136];   // 34816 B  -> total 71680 B
    const int w = threadIdx.x >> 6;
    const int l = threadIdx.x & 63;
    const int lane15 = l & 15;
    const int quad = l >> 4;
    const int rowBase = blockIdx.x * 128;

    // ---- phase 0: gather means for this block's rows ----
    {
        int n_ovf = *ovfc;
        if (n_ovf > OVF_CAP) n_ovf = OVF_CAP;
        const int fb0 = quad * 8;        // feature octet 1 (in 0..31)
        const int fb1 = 32 + quad * 8;   // feature octet 2 (in 32..63)
#pragma unroll
        for (int pass = 0; pass < 2; ++pass) {
            const int rloc = w * 32 + pass * 16 + lane15;
            const int row = rowBase + rloc;
            const bool rv = row < N_NODES;
            int deg = rv ? counts[row] : 0;
            int dcap = min(deg, DEG_CAP);
            float s[16];
#pragma unroll
            for (int i = 0; i < 16; ++i) s[i] = 0.f;
            int j = 0;
            for (; j + 2 <= dcap; j += 2) {
                int id0 = slots[row * DEG_CAP + j];
                int id1 = slots[row * DEG_CAP + j + 1];
                uint4 a0 = *(const uint4*)(xh + id0 * 64 + fb0);
                uint4 b0 = *(const uint4*)(xh + id0 * 64 + fb1);
                uint4 a1 = *(const uint4*)(xh + id1 * 64 + fb0);
                uint4 b1v = *(const uint4*)(xh + id1 * 64 + fb1);
                s[0] += bflo(a0.x) + bflo(a1.x);  s[1] += bfhi(a0.x) + bfhi(a1.x);
                s[2] += bflo(a0.y) + bflo(a1.y);  s[3] += bfhi(a0.y) + bfhi(a1.y);
                s[4] += bflo(a0.z) + bflo(a1.z);  s[5] += bfhi(a0.z) + bfhi(a1.z);
                s[6] += bflo(a0.w) + bflo(a1.w);  s[7] += bfhi(a0.w) + bfhi(a1.w);
                s[8]  += bflo(b0.x) + bflo(b1v.x); s[9]  += bfhi(b0.x) + bfhi(b1v.x);
                s[10] += bflo(b0.y) + bflo(b1v.y); s[11] += bfhi(b0.y) + bfhi(b1v.y);
                s[12] += bflo(b0.z) + bflo(b1v.z); s[13] += bfhi(b0.z) + bfhi(b1v.z);
                s[14] += bflo(b0.w) + bflo(b1v.w); s[15] += bfhi(b0.w) + bfhi(b1v.w);
            }
            if (j < dcap) {
                int id0 = slots[row * DEG_CAP + j];
                uint4 a0 = *(const uint4*)(xh + id0 * 64 + fb0);
                uint4 b0 = *(const uint4*)(xh + id0 * 64 + fb1);
                s[0] += bflo(a0.x);  s[1] += bfhi(a0.x);
                s[2] += bflo(a0.y);  s[3] += bfhi(a0.y);
                s[4] += bflo(a0.z);  s[5] += bfhi(a0.z);
                s[6] += bflo(a0.w);  s[7] += bfhi(a0.w);
                s[8]  += bflo(b0.x); s[9]  += bfhi(b0.x);
                s[10] += bflo(b0.y); s[11] += bfhi(b0.y);
                s[12] += bflo(b0.z); s[13] += bfhi(b0.z);
                s[14] += bflo(b0.w); s[15] += bfhi(b0.w);
            }
            float inv = 1.0f / fmaxf((float)deg, 1.0f);
            float m[16];
#pragma unroll
            for (int i = 0; i < 16; ++i) m[i] = s[i] * inv;
            // layer-1 overflow contributions (n_ovf ~ 0)
            for (int idx = 0; idx < n_ovf; ++idx) {
                if (ovf[idx * 2 + 1] == row) {
                    int sx = ovf[idx * 2];
#pragma unroll
                    for (int i = 0; i < 8; ++i) {
                        m[i]     += x[sx * 64 + fb0 + i] * inv;
                        m[8 + i] += x[sx * 64 + fb1 + i] * inv;
                    }
                }
            }
            unsigned short hh[16], ll[16];
#pragma unroll
            for (int i = 0; i < 16; ++i) split_rbf(m[i], hh[i], ll[i]);
            ushort4 v;
            v.x = hh[0]; v.y = hh[1]; v.z = hh[2]; v.w = hh[3];
            *(ushort4*)&mean_h[rloc][fb0] = v;
            v.x = hh[4]; v.y = hh[5]; v.z = hh[6]; v.w = hh[7];
            *(ushort4*)&mean_h[rloc][fb0 + 4] = v;
            v.x = hh[8]; v.y = hh[9]; v.z = hh[10]; v.w = hh[11];
            *(ushort4*)&mean_h[rloc][fb1] = v;
            v.x = hh[12]; v.y = hh[13]; v.z = hh[14]; v.w = hh[15];
            *(ushort4*)&mean_h[rloc][fb1 + 4] = v;
            v.x = ll[0]; v.y = ll[1]; v.z = ll[2]; v.w = ll[3];
            *(ushort4*)&mean_l[rloc][fb0] = v;
            v.x = ll[4]; v.y = ll[5]; v.z = ll[6]; v.w = ll[7];
            *(ushort4*)&mean_l[rloc][fb0 + 4] = v;
            v.x = ll[8]; v.y = ll[9]; v.z = ll[10]; v.w = ll[11];
            *(ushort4*)&mean_l[rloc][fb1] = v;
            v.x = ll[12]; v.y = ll[13]; v.z = ll[14]; v.w = ll[15];
            *(ushort4*)&mean_l[rloc][fb1 + 4] = v;
        }
    }
    __syncthreads();

    // ---- phase 1: layer 1, B-stationary, 3-MFMA hi/lo split ----
    {
        bf16x8 bh[2][4], bl[2][4];
#pragma unroll
        for (int ci = 0; ci < 2; ++ci) {
            const int c = 2 * w + ci;
#pragma unroll
            for (int kc = 0; kc < 4; ++kc) {
                const short* bp = Bf1 + ((c * 4 + kc) * 2) * 512 + l * 8;
                bh[ci][kc] = *(const bf16x8*)bp;
                bl[ci][kc] = *(const bf16x8*)(bp + 512);
            }
        }
        float bias[2];
#pragma unroll
        for (int ci = 0; ci < 2; ++ci) bias[ci] = b1[(2 * w + ci) * 16 + lane15];

        const bf16x8 zz = {0, 0, 0, 0, 0, 0, 0, 0};
        auto load_x = [&](int rt, bf16x8 (&xhf)[2], bf16x8 (&xlf)[2]) {
            const int row = rowBase + rt * 16 + lane15;
            const bool rv = row < N_NODES;
#pragma unroll
            for (int kk = 0; kk < 2; ++kk) {
                if (rv) {
                    const int off = row * 64 + kk * 32 + quad * 8;
                    xhf[kk] = *(const bf16x8*)(xh + off);
                    xlf[kk] = *(const bf16x8*)(xl + off);
                } else {
                    xhf[kk] = zz;
                    xlf[kk] = zz;
                }
            }
        };
        auto compute_store = [&](bf16x8 (&xhf)[2], bf16x8 (&xlf)[2], int rt) {
            const int rl = rt * 16 + lane15;
            bf16x8 mh0 = *(const bf16x8*)&mean_h[rl][quad * 8];
            bf16x8 mh1 = *(const bf16x8*)&mean_h[rl][32 + quad * 8];
            bf16x8 ml0 = *(const bf16x8*)&mean_l[rl][quad * 8];
            bf16x8 ml1 = *(const bf16x8*)&mean_l[rl][32 + quad * 8];
            bf16x8 ah[4] = {mh0, mh1, xhf[0], xhf[1]};
            bf16x8 al[4] = {ml0, ml1, xlf[0], xlf[1]};
            f32x4 acc[2] = {(f32x4){0.f, 0.f, 0.f, 0.f},
                            (f32x4){0.f, 0.f, 0.f, 0.f}};
#pragma unroll
            for (int kc = 0; kc < 4; ++kc) {
#pragma unroll
                for (int ci = 0; ci < 2; ++ci) {
                    acc[ci] = __builtin_amdgcn_mfma_f32_16x16x32_bf16(ah[kc], bh[ci][kc], acc[ci], 0, 0, 0);
                    acc[ci] = __builtin_amdgcn_mfma_f32_16x16x32_bf16(al[kc], bh[ci][kc], acc[ci], 0, 0, 0);
                    acc[ci] = __builtin_amdgcn_mfma_f32_16x16x32_bf16(ah[kc], bl[ci][kc], acc[ci], 0, 0, 0);
                }
            }
            const int rloc = rt * 16 + quad * 4;
#pragma unroll
            for (int ci = 0; ci < 2; ++ci) {
                const int col = (2 * w + ci) * 16 + lane15;
#pragma unroll
                for (int i = 0; i < 4; ++i)
                    h_lds[rloc + i][col] =
                        f2bf(fmaxf(acc[ci][i] + bias[ci], 0.f));
            }
        };

        bf16x8 xhA[2], xlA[2], xhB[2], xlB[2];
        load_x(0, xhA, xlA);
#pragma unroll
        for (int rt = 0; rt < 8; rt += 2) {
            load_x(rt + 1, xhB, xlB);
            compute_store(xhA, xlA, rt);
            if (rt + 2 < 8) load_x(rt + 2, xhA, xlA);
            compute_store(xhB, xlB, rt + 1);
        }
    }
    __syncthreads();

    // ---- phase 2: layer 2 from LDS (A = bf16, W2 keeps hi/lo split) ----
    {
        bf16x8 bh[2][4], bl[2][4];
#pragma unroll
        for (int ci = 0; ci < 2; ++ci) {
            const int c = 2 * w + ci;
#pragma unroll
            for (int kc = 0; kc < 4; ++kc) {
                const short* bp = Bf2 + ((c * 4 + kc) * 2) * 512 + l * 8;
                bh[ci][kc] = *(const bf16x8*)bp;
                bl[ci][kc] = *(const bf16x8*)(bp + 512);
            }
        }
        float bias[2];
#pragma unroll
        for (int ci = 0; ci < 2; ++ci) {
            const int c = 2 * w + ci;
            bias[ci] = (c >= 4) ? b2[(c - 4) * 16 + lane15] : 0.f;
        }

#pragma unroll
        for (int rt = 0; rt < 8; ++rt) {
            bf16x8 ah[4];
#pragma unroll
            for (int kc = 0; kc < 4; ++kc)
                ah[kc] = *(const bf16x8*)&h_lds[rt * 16 + lane15][kc * 32 + quad * 8];

            f32x4 acc[2] = {(f32x4){0.f, 0.f, 0.f, 0.f}, (f32x4){0.f, 0.f, 0.f, 0.f}};
#pragma unroll
            for (int kc = 0; kc < 4; ++kc) {
#pragma unroll
                for (int ci = 0; ci < 2; ++ci) {
                    acc[ci] = __builtin_amdgcn_mfma_f32_16x16x32_bf16(ah[kc], bh[ci][kc], acc[ci], 0, 0, 0);
                    acc[ci] = __builtin_amdgcn_mfma_f32_16x16x32_bf16(ah[kc], bl[ci][kc], acc[ci], 0, 0, 0);
                }
            }

            const int rb = rowBase + rt * 16 + quad * 4;
#pragma unroll
            for (int ci = 0; ci < 2; ++ci) {
                const int c = 2 * w + ci;
                if (c < 4) {
#pragma unroll
                    for (int i = 0; i < 4; ++i) {
                        int r = rb + i;
                        if (r < N_NODES)
                            p_bf_out[r * 64 + c * 16 + lane15] = f2bf(acc[ci][i]);
                    }
                } else {
#pragma unroll
                    for (int i = 0; i < 4; ++i) {
                        int r = rb + i;
                        if (r < N_NODES)
                            q[r * 64 + (c - 4) * 16 + lane15] = acc[ci][i] + bias[ci];
                    }
                }
            }
        }
    }
}

// Layer-2 gather + epilogue, 16-lane-group-per-node.
// out = mean(p_bf[nbrs]) + q, ovf added inline.
__global__ __launch_bounds__(256) void gather_final_kernel(
        const unsigned short* __restrict__ p, const int* __restrict__ counts,
        const int* __restrict__ slots, const float* __restrict__ q,
        const int* __restrict__ ovf, const int* __restrict__ ovfc,
        float* __restrict__ out) {
    int node = blockIdx.x * 16 + (threadIdx.x >> 4);
    int t = threadIdx.x & 15;
    if (node >= N_NODES) return;
    int deg = counts[node];
    int dcap = min(deg, DEG_CAP);
    const int gbase = threadIdx.x & 48;
    float a0 = 0.f, a1 = 0.f, a2 = 0.f, a3 = 0.f;
    for (int phase = 0; phase * 16 < dcap; ++phase) {
        int ids16 = slots[node * DEG_CAP + phase * 16 + t];
        int lim = min(dcap - phase * 16, 16);
        int j = 0;
        for (; j + 4 <= lim; j += 4) {
            int s0 = __shfl(ids16, gbase | (j + 0));
            int s1 = __shfl(ids16, gbase | (j + 1));
            int s2 = __shfl(ids16, gbase | (j + 2));
            int s3 = __shfl(ids16, gbase | (j + 3));
            uint2 u0 = *(const uint2*)(p + s0 * 64 + t * 4);
            uint2 u1 = *(const uint2*)(p + s1 * 64 + t * 4);
            uint2 u2 = *(const uint2*)(p + s2 * 64 + t * 4);
            uint2 u3 = *(const uint2*)(p + s3 * 64 + t * 4);
            a0 += bflo(u0.x) + bflo(u1.x) + bflo(u2.x) + bflo(u3.x);
            a1 += bfhi(u0.x) + bfhi(u1.x) + bfhi(u2.x) + bfhi(u3.x);
            a2 += bflo(u0.y) + bflo(u1.y) + bflo(u2.y) + bflo(u3.y);
            a3 += bfhi(u0.y) + bfhi(u1.y) + bfhi(u2.y) + bfhi(u3.y);
        }
        for (; j < lim; ++j) {
            int s = __shfl(ids16, gbase | j);
            uint2 u = *(const uint2*)(p + s * 64 + t * 4);
            a0 += bflo(u.x);
            a1 += bfhi(u.x);
            a2 += bflo(u.y);
            a3 += bfhi(u.y);
        }
    }
    // inline layer-2 overflow additions (n is ~always 0)
    int n = *ovfc;
    if (n > OVF_CAP) n = OVF_CAP;
    for (int idx = 0; idx < n; ++idx) {
        if (ovf[idx * 2 + 1] == node) {
            int s = ovf[idx * 2];
            uint2 u = *(const uint2*)(p + s * 64 + t * 4);
            a0 += bflo(u.x);
            a1 += bfhi(u.x);
            a2 += bflo(u.y);
            a3 += bfhi(u.y);
        }
    }
    float inv = 1.0f / fmaxf((float)deg, 1.0f);
    float4 qv = *(const float4*)&q[node * 64 + t * 4];
    *(float4*)&out[node * 64 + t * 4] =
        make_float4(a0 * inv + qv.x, a1 * inv + qv.y,
                    a2 * inv + qv.z, a3 * inv + qv.w);
}

extern "C" void kernel_launch(void* const* d_in, const int* in_sizes, int n_in,
                              void* d_out, int out_size, void* d_ws, size_t ws_size,
                              hipStream_t stream) {
    const float* x   = (const float*)d_in[0];
    const float* W1l = (const float*)d_in[1];
    const float* W1r = (const float*)d_in[2];
    const float* b1  = (const float*)d_in[3];
    const float* W2l = (const float*)d_in[4];
    const float* W2r = (const float*)d_in[5];
    const float* b2  = (const float*)d_in[6];
    const int*   ei  = (const int*)d_in[7];

    int*   wsi      = (int*)d_ws;
    float* wsf      = (float*)d_ws;
    int*   counts   = wsi;
    int*   ovfc     = wsi + 100352;
    int*   spillc   = wsi + 100353;
    int*   gcur     = wsi + 100416;
    int*   ovf      = wsi + 100928;
    int2*  spill    = (int2*)(wsi + 109120);
    short* Bf1      = (short*)(wsi + 117312);
    short* Bf2      = (short*)(wsi + 133696);
    int*   slots    = wsi + 150080;
    unsigned* rec   = (unsigned*)(wsi + 6572608);
    unsigned short* xh = (unsigned short*)(wsi + 8178240);
    unsigned short* xl = (unsigned short*)(wsi + 11378240);
    unsigned short* p_bf = (unsigned short*)(wsi + 20978240);
    float* q        = wsf + 24178240;
    float* out      = (float*)d_out;

    prep_kernel<<<(N_NODES * 16 + 255) / 256, 256, 0, stream>>>(
        (const float4*)x, (ushort4*)xh, (ushort4*)xl, W1l, W1r, W2l, W2r,
        Bf1, Bf2, (int4*)gcur, ovfc, spillc);

    // indexing: LDS-binned two-pass (spill handled inside build)
    bin_kernel<<<(N_EDGES + BIN_CHUNK - 1) / BIN_CHUNK, 256, 0, stream>>>(
        ei, rec, gcur, spillc, spill);
    build_kernel<<<NBKT, 256, 0, stream>>>(
        rec, gcur, spill, spillc, counts, slots, ovfc, ovf);

    // fused gather + MLP: means (LDS) -> h (LDS) -> p_bf, q
    mlp_fused_kernel<<<(N_NODES + 127) / 128, 256, 0, stream>>>(
        xh, xl, x, counts, slots, Bf1, b1, Bf2, b2, ovf, ovfc, p_bf, q);

    // fused layer-2 aggregation + epilogue (ovf additions inside)
    gather_final_kernel<<<(N_NODES + 15) / 16, 256, 0, stream>>>(
        p_bf, counts, slots, q, ovf, ovfc, out);
}

// Round 14
// 204.465 us; speedup vs baseline: 1.0600x; 1.0398x over previous
//
#include <hip/hip_runtime.h>

#define N_NODES 100000
#define N_EDGES 1000000
#define DEG_CAP 64
#define OVF_CAP 4096
#define SPILL_CAP 4096

// binning geometry
#define BKT_SH 8
#define BKT_NODES 256            // nodes per bucket
#define NBKT 392                 // 392*256 = 100352 >= N_NODES
#define BKT_CAP 4096             // record capacity per bucket (mean ~2551)
#define BIN_CHUNK 4096           // edges per bin block
#define FIFO_CAP 32              // LDS fifo depth per bucket (mean ~10.4)

typedef __attribute__((ext_vector_type(8))) short bf16x8;
typedef __attribute__((ext_vector_type(4))) float f32x4;

__device__ __forceinline__ unsigned short f2bf(float f) {
    unsigned u = __float_as_uint(f);
    return (unsigned short)((u + 0x7FFF + ((u >> 16) & 1)) >> 16);
}
__device__ __forceinline__ float bf2f(unsigned short b) {
    return __uint_as_float(((unsigned)b) << 16);
}
__device__ __forceinline__ float bflo(unsigned u) {   // low bf16 of a dword
    return __uint_as_float(u << 16);
}
__device__ __forceinline__ float bfhi(unsigned u) {   // high bf16 of a dword
    return __uint_as_float(u & 0xffff0000u);
}
// rounded hi + rounded residual lo (kept for WEIGHTS only — mean/x lo
// planes measured numerically negligible and dropped this round).
__device__ __forceinline__ void split_rbf(float f, unsigned short& ho,
                                          unsigned short& lo) {
    unsigned short hb = f2bf(f);
    ho = hb;
    lo = f2bf(f - bf2f(hb));
}

// ws layout (4B units) — AUDITED (u16 plane = N*64 u16 = 3,200,000 dwords):
//   counts : [0, 100352)
//   ovfc 100352 ; spillc 100353
//   gcur   : [100416, 100928)
//   ovf    : [100928, 109120)
//   spill  : [109120, 117312)
//   Bf1    : s16 [117312, 133696)
//   Bf2    : s16 [133696, 150080)
//   slots  : [150080, 6572608)        100352*64 dwords
//   rec    : u32 [6572608, 8178240)   392*4096
//   xh     : u16 [8178240,  11378240) 3.2M dwords = 6.4M u16
//   (xl/mh/ml regions unused — lo planes dropped, gather fused)
//   p_bf   : u16 [20978240, 24178240)
//   q      : f32 [24178240, 30578240)
// total 30,578,240 dwords = 122.3 MB

// Merged init + weight-split + x -> rounded bf16 plane.
__global__ __launch_bounds__(256) void prep_kernel(
        const float4* __restrict__ x4, ushort4* __restrict__ xh4,
        const float* __restrict__ W1l, const float* __restrict__ W1r,
        const float* __restrict__ W2l, const float* __restrict__ W2r,
        short* __restrict__ Bf1, short* __restrict__ Bf2,
        int4* __restrict__ gcur4, int* __restrict__ ovfc,
        int* __restrict__ spillc) {
    int i = blockIdx.x * blockDim.x + threadIdx.x;
    if (i < 128) gcur4[i] = make_int4(0, 0, 0, 0);
    if (i == 0) { *ovfc = 0; *spillc = 0; }
    if (i < 32768) {
        int g = i >> 14;
        int e = i & 16383;
        int k = e >> 7;
        int n = e & 127;
        float v;
        if (g == 0) v = (k < 64) ? W1l[k * 128 + n] : W1r[(k - 64) * 128 + n];
        else        v = (n < 64) ? W2l[k * 64 + n]  : W2r[k * 64 + (n - 64)];
        unsigned short hb, lb;
        split_rbf(v, hb, lb);
        int c = n >> 4, kc = k >> 5;
        int lane = (((k >> 3) & 3) << 4) | (n & 15);
        int j = k & 7;
        short* base = g ? Bf2 : Bf1;
        base[((c * 4 + kc) * 2 + 0) * 512 + lane * 8 + j] = (short)hb;
        base[((c * 4 + kc) * 2 + 1) * 512 + lane * 8 + j] = (short)lb;
    }
    if (i < N_NODES * 16) {
        float4 v = x4[i];
        ushort4 oh;
        oh.x = f2bf(v.x);
        oh.y = f2bf(v.y);
        oh.z = f2bf(v.z);
        oh.w = f2bf(v.w);
        xh4[i] = oh;
    }
}

// Pass A: bin edges into 392 dst-range buckets via LDS FIFOs.
__global__ __launch_bounds__(256) void bin_kernel(
        const int* __restrict__ ei, unsigned* __restrict__ rec,
        int* __restrict__ gcur, int* __restrict__ spillc,
        int2* __restrict__ spill) {
    __shared__ int lcnt[NBKT];
    __shared__ unsigned fifo[NBKT * FIFO_CAP];   // 50KB
    for (int i = threadIdx.x; i < NBKT; i += 256) lcnt[i] = 0;
    __syncthreads();
    int base = blockIdx.x * BIN_CHUNK;
    int end = base + BIN_CHUNK;
    if (end > N_EDGES) end = N_EDGES;
    for (int e = base + threadIdx.x; e < end; e += 256) {
        int s = ei[e];
        int d = ei[N_EDGES + e];
        int b = d >> BKT_SH;
        unsigned r = ((unsigned)s << BKT_SH) | (unsigned)(d & (BKT_NODES - 1));
        int pos = atomicAdd(&lcnt[b], 1);
        if (pos < FIFO_CAP) {
            fifo[b * FIFO_CAP + pos] = r;
        } else {
            int o = atomicAdd(spillc, 1);
            if (o < SPILL_CAP) spill[o] = make_int2(s, d);
        }
    }
    __syncthreads();
    for (int b = threadIdx.x; b < NBKT; b += 256) {
        int cnt = lcnt[b];
        if (cnt > FIFO_CAP) cnt = FIFO_CAP;
        if (cnt == 0) continue;
        int gb = atomicAdd(&gcur[b], cnt);
        for (int k = 0; k < cnt; ++k) {
            int g = gb + k;
            unsigned r = fifo[b * FIFO_CAP + k];
            if (g < BKT_CAP) {
                rec[b * BKT_CAP + g] = r;
            } else {
                int o = atomicAdd(spillc, 1);
                if (o < SPILL_CAP)
                    spill[o] = make_int2((int)(r >> BKT_SH),
                                         (b << BKT_SH) | (int)(r & (BKT_NODES - 1)));
            }
        }
    }
}

// Pass B: one block per bucket; counts + slots tile built in LDS (65KB),
// written out fully coalesced. Spill entries handled inline.
__global__ __launch_bounds__(256) void build_kernel(
        const unsigned* __restrict__ rec, const int* __restrict__ gcur,
        const int2* __restrict__ spill, const int* __restrict__ spillc,
        int* __restrict__ counts, int* __restrict__ slots,
        int* __restrict__ ovfc, int* __restrict__ ovf) {
    __shared__ int lcnt[BKT_NODES];
    __shared__ int lslots[BKT_NODES * DEG_CAP];   // 64KB
    int b = blockIdx.x;
    for (int i = threadIdx.x; i < BKT_NODES; i += 256) lcnt[i] = 0;
    __syncthreads();
    int n = gcur[b];
    if (n > BKT_CAP) n = BKT_CAP;
    for (int i = threadIdx.x; i < n; i += 256) {
        unsigned r = rec[b * BKT_CAP + i];
        int dlo = (int)(r & (BKT_NODES - 1));
        int src = (int)(r >> BKT_SH);
        int pos = atomicAdd(&lcnt[dlo], 1);
        if (pos < DEG_CAP) {
            lslots[dlo * DEG_CAP + pos] = src;
        } else {
            int o = atomicAdd(ovfc, 1);
            if (o < OVF_CAP) {
                ovf[o * 2] = src;
                ovf[o * 2 + 1] = (b << BKT_SH) | dlo;
            }
        }
    }
    // inline spill handling (usually ns == 0)
    int ns = *spillc;
    if (ns > SPILL_CAP) ns = SPILL_CAP;
    for (int i = threadIdx.x; i < ns; i += 256) {
        int2 e = spill[i];
        if ((e.y >> BKT_SH) == b) {
            int dlo = e.y & (BKT_NODES - 1);
            int pos = atomicAdd(&lcnt[dlo], 1);
            if (pos < DEG_CAP) {
                lslots[dlo * DEG_CAP + pos] = e.x;
            } else {
                int o = atomicAdd(ovfc, 1);
                if (o < OVF_CAP) { ovf[o * 2] = e.x; ovf[o * 2 + 1] = e.y; }
            }
        }
    }
    __syncthreads();
    int nodeBase = b << BKT_SH;
    for (int i = threadIdx.x; i < BKT_NODES; i += 256)
        counts[nodeBase + i] = lcnt[i];
    const int4* ls4 = (const int4*)lslots;
    int4* gs4 = (int4*)(slots + nodeBase * DEG_CAP);
    for (int i = threadIdx.x; i < BKT_NODES * DEG_CAP / 4; i += 256)
        gs4[i] = ls4[i];
}

// FUSED gather + MLP, 128-row tiles, 4 waves × 2 col-tiles.
// Lo-planes for mean and x DROPPED (error budget: mean-lo ~6e-4,
// x-lo ~0.01 vs threshold headroom 0.031->0.098). Weights keep hi/lo.
// LDS: 18KB mean + 34.8KB h = 53.2KB -> 3 blocks/CU (was 2).
// Phase-1 MFMAs: 16/rt (was 24); x loads halved.
__global__ __launch_bounds__(256) void mlp_fused_kernel(
        const unsigned short* __restrict__ xh,
        const float* __restrict__ x,
        const int* __restrict__ counts, const int* __restrict__ slots,
        const short* __restrict__ Bf1, const float* __restrict__ b1,
        const short* __restrict__ Bf2, const float* __restrict__ b2,
        const int* __restrict__ ovf, const int* __restrict__ ovfc,
        unsigned short* __restrict__ p_bf_out, float* __restrict__ q) {
    __shared__ unsigned short mean_h[128][72];   // 18432 B (144B row stride)
    __shared__ unsigned short h_lds[128][136];   // 34816 B -> total 53248 B
    const int w = threadIdx.x >> 6;
    const int l = threadIdx.x & 63;
    const int lane15 = l & 15;
    const int quad = l >> 4;
    const int rowBase = blockIdx.x * 128;

    // ---- phase 0: gather means for this block's rows ----
    {
        int n_ovf = *ovfc;
        if (n_ovf > OVF_CAP) n_ovf = OVF_CAP;
        const int fb0 = quad * 8;        // feature octet 1 (in 0..31)
        const int fb1 = 32 + quad * 8;   // feature octet 2 (in 32..63)
#pragma unroll
        for (int pass = 0; pass < 2; ++pass) {
            const int rloc = w * 32 + pass * 16 + lane15;
            const int row = rowBase + rloc;
            const bool rv = row < N_NODES;
            int deg = rv ? counts[row] : 0;
            int dcap = min(deg, DEG_CAP);
            float s[16];
#pragma unroll
            for (int i = 0; i < 16; ++i) s[i] = 0.f;
            int j = 0;
            for (; j + 2 <= dcap; j += 2) {
                int id0 = slots[row * DEG_CAP + j];
                int id1 = slots[row * DEG_CAP + j + 1];
                uint4 a0 = *(const uint4*)(xh + id0 * 64 + fb0);
                uint4 b0 = *(const uint4*)(xh + id0 * 64 + fb1);
                uint4 a1 = *(const uint4*)(xh + id1 * 64 + fb0);
                uint4 b1v = *(const uint4*)(xh + id1 * 64 + fb1);
                s[0] += bflo(a0.x) + bflo(a1.x);  s[1] += bfhi(a0.x) + bfhi(a1.x);
                s[2] += bflo(a0.y) + bflo(a1.y);  s[3] += bfhi(a0.y) + bfhi(a1.y);
                s[4] += bflo(a0.z) + bflo(a1.z);  s[5] += bfhi(a0.z) + bfhi(a1.z);
                s[6] += bflo(a0.w) + bflo(a1.w);  s[7] += bfhi(a0.w) + bfhi(a1.w);
                s[8]  += bflo(b0.x) + bflo(b1v.x); s[9]  += bfhi(b0.x) + bfhi(b1v.x);
                s[10] += bflo(b0.y) + bflo(b1v.y); s[11] += bfhi(b0.y) + bfhi(b1v.y);
                s[12] += bflo(b0.z) + bflo(b1v.z); s[13] += bfhi(b0.z) + bfhi(b1v.z);
                s[14] += bflo(b0.w) + bflo(b1v.w); s[15] += bfhi(b0.w) + bfhi(b1v.w);
            }
            if (j < dcap) {
                int id0 = slots[row * DEG_CAP + j];
                uint4 a0 = *(const uint4*)(xh + id0 * 64 + fb0);
                uint4 b0 = *(const uint4*)(xh + id0 * 64 + fb1);
                s[0] += bflo(a0.x);  s[1] += bfhi(a0.x);
                s[2] += bflo(a0.y);  s[3] += bfhi(a0.y);
                s[4] += bflo(a0.z);  s[5] += bfhi(a0.z);
                s[6] += bflo(a0.w);  s[7] += bfhi(a0.w);
                s[8]  += bflo(b0.x); s[9]  += bfhi(b0.x);
                s[10] += bflo(b0.y); s[11] += bfhi(b0.y);
                s[12] += bflo(b0.z); s[13] += bfhi(b0.z);
                s[14] += bflo(b0.w); s[15] += bfhi(b0.w);
            }
            float inv = 1.0f / fmaxf((float)deg, 1.0f);
            float m[16];
#pragma unroll
            for (int i = 0; i < 16; ++i) m[i] = s[i] * inv;
            // layer-1 overflow contributions (n_ovf ~ 0)
            for (int idx = 0; idx < n_ovf; ++idx) {
                if (ovf[idx * 2 + 1] == row) {
                    int sx = ovf[idx * 2];
#pragma unroll
                    for (int i = 0; i < 8; ++i) {
                        m[i]     += x[sx * 64 + fb0 + i] * inv;
                        m[8 + i] += x[sx * 64 + fb1 + i] * inv;
                    }
                }
            }
            unsigned short hh[16];
#pragma unroll
            for (int i = 0; i < 16; ++i) hh[i] = f2bf(m[i]);
            ushort4 v;
            v.x = hh[0]; v.y = hh[1]; v.z = hh[2]; v.w = hh[3];
            *(ushort4*)&mean_h[rloc][fb0] = v;
            v.x = hh[4]; v.y = hh[5]; v.z = hh[6]; v.w = hh[7];
            *(ushort4*)&mean_h[rloc][fb0 + 4] = v;
            v.x = hh[8]; v.y = hh[9]; v.z = hh[10]; v.w = hh[11];
            *(ushort4*)&mean_h[rloc][fb1] = v;
            v.x = hh[12]; v.y = hh[13]; v.z = hh[14]; v.w = hh[15];
            *(ushort4*)&mean_h[rloc][fb1 + 4] = v;
        }
    }
    __syncthreads();

    // ---- phase 1: layer 1, B-stationary, A=bf16, W hi/lo (2 MFMA) ----
    {
        bf16x8 bh[2][4], bl[2][4];
#pragma unroll
        for (int ci = 0; ci < 2; ++ci) {
            const int c = 2 * w + ci;
#pragma unroll
            for (int kc = 0; kc < 4; ++kc) {
                const short* bp = Bf1 + ((c * 4 + kc) * 2) * 512 + l * 8;
                bh[ci][kc] = *(const bf16x8*)bp;
                bl[ci][kc] = *(const bf16x8*)(bp + 512);
            }
        }
        float bias[2];
#pragma unroll
        for (int ci = 0; ci < 2; ++ci) bias[ci] = b1[(2 * w + ci) * 16 + lane15];

        const bf16x8 zz = {0, 0, 0, 0, 0, 0, 0, 0};
        auto load_x = [&](int rt, bf16x8 (&xhf)[2]) {
            const int row = rowBase + rt * 16 + lane15;
            const bool rv = row < N_NODES;
#pragma unroll
            for (int kk = 0; kk < 2; ++kk) {
                if (rv) {
                    const int off = row * 64 + kk * 32 + quad * 8;
                    xhf[kk] = *(const bf16x8*)(xh + off);
                } else {
                    xhf[kk] = zz;
                }
            }
        };
        auto compute_store = [&](bf16x8 (&xhf)[2], int rt) {
            const int rl = rt * 16 + lane15;
            bf16x8 mh0 = *(const bf16x8*)&mean_h[rl][quad * 8];
            bf16x8 mh1 = *(const bf16x8*)&mean_h[rl][32 + quad * 8];
            bf16x8 ah[4] = {mh0, mh1, xhf[0], xhf[1]};
            f32x4 acc[2] = {(f32x4){0.f, 0.f, 0.f, 0.f},
                            (f32x4){0.f, 0.f, 0.f, 0.f}};
#pragma unroll
            for (int kc = 0; kc < 4; ++kc) {
#pragma unroll
                for (int ci = 0; ci < 2; ++ci) {
                    acc[ci] = __builtin_amdgcn_mfma_f32_16x16x32_bf16(ah[kc], bh[ci][kc], acc[ci], 0, 0, 0);
                    acc[ci] = __builtin_amdgcn_mfma_f32_16x16x32_bf16(ah[kc], bl[ci][kc], acc[ci], 0, 0, 0);
                }
            }
            const int rloc = rt * 16 + quad * 4;
#pragma unroll
            for (int ci = 0; ci < 2; ++ci) {
                const int col = (2 * w + ci) * 16 + lane15;
#pragma unroll
                for (int i = 0; i < 4; ++i)
                    h_lds[rloc + i][col] =
                        f2bf(fmaxf(acc[ci][i] + bias[ci], 0.f));
            }
        };

        bf16x8 xhA[2], xhB[2];
        load_x(0, xhA);
#pragma unroll
        for (int rt = 0; rt < 8; rt += 2) {
            load_x(rt + 1, xhB);
            compute_store(xhA, rt);
            if (rt + 2 < 8) load_x(rt + 2, xhA);
            compute_store(xhB, rt + 1);
        }
    }
    __syncthreads();

    // ---- phase 2: layer 2 from LDS (A = bf16, W2 keeps hi/lo split) ----
    {
        bf16x8 bh[2][4], bl[2][4];
#pragma unroll
        for (int ci = 0; ci < 2; ++ci) {
            const int c = 2 * w + ci;
#pragma unroll
            for (int kc = 0; kc < 4; ++kc) {
                const short* bp = Bf2 + ((c * 4 + kc) * 2) * 512 + l * 8;
                bh[ci][kc] = *(const bf16x8*)bp;
                bl[ci][kc] = *(const bf16x8*)(bp + 512);
            }
        }
        float bias[2];
#pragma unroll
        for (int ci = 0; ci < 2; ++ci) {
            const int c = 2 * w + ci;
            bias[ci] = (c >= 4) ? b2[(c - 4) * 16 + lane15] : 0.f;
        }

#pragma unroll
        for (int rt = 0; rt < 8; ++rt) {
            bf16x8 ah[4];
#pragma unroll
            for (int kc = 0; kc < 4; ++kc)
                ah[kc] = *(const bf16x8*)&h_lds[rt * 16 + lane15][kc * 32 + quad * 8];

            f32x4 acc[2] = {(f32x4){0.f, 0.f, 0.f, 0.f}, (f32x4){0.f, 0.f, 0.f, 0.f}};
#pragma unroll
            for (int kc = 0; kc < 4; ++kc) {
#pragma unroll
                for (int ci = 0; ci < 2; ++ci) {
                    acc[ci] = __builtin_amdgcn_mfma_f32_16x16x32_bf16(ah[kc], bh[ci][kc], acc[ci], 0, 0, 0);
                    acc[ci] = __builtin_amdgcn_mfma_f32_16x16x32_bf16(ah[kc], bl[ci][kc], acc[ci], 0, 0, 0);
                }
            }

            const int rb = rowBase + rt * 16 + quad * 4;
#pragma unroll
            for (int ci = 0; ci < 2; ++ci) {
                const int c = 2 * w + ci;
                if (c < 4) {
#pragma unroll
                    for (int i = 0; i < 4; ++i) {
                        int r = rb + i;
                        if (r < N_NODES)
                            p_bf_out[r * 64 + c * 16 + lane15] = f2bf(acc[ci][i]);
                    }
                } else {
#pragma unroll
                    for (int i = 0; i < 4; ++i) {
                        int r = rb + i;
                        if (r < N_NODES)
                            q[r * 64 + (c - 4) * 16 + lane15] = acc[ci][i] + bias[ci];
                    }
                }
            }
        }
    }
}

// Layer-2 gather + epilogue, 16-lane-group-per-node.
// out = mean(p_bf[nbrs]) + q, ovf added inline.
__global__ __launch_bounds__(256) void gather_final_kernel(
        const unsigned short* __restrict__ p, const int* __restrict__ counts,
        const int* __restrict__ slots, const float* __restrict__ q,
        const int* __restrict__ ovf, const int* __restrict__ ovfc,
        float* __restrict__ out) {
    int node = blockIdx.x * 16 + (threadIdx.x >> 4);
    int t = threadIdx.x & 15;
    if (node >= N_NODES) return;
    int deg = counts[node];
    int dcap = min(deg, DEG_CAP);
    const int gbase = threadIdx.x & 48;
    float a0 = 0.f, a1 = 0.f, a2 = 0.f, a3 = 0.f;
    for (int phase = 0; phase * 16 < dcap; ++phase) {
        int ids16 = slots[node * DEG_CAP + phase * 16 + t];
        int lim = min(dcap - phase * 16, 16);
        int j = 0;
        for (; j + 4 <= lim; j += 4) {
            int s0 = __shfl(ids16, gbase | (j + 0));
            int s1 = __shfl(ids16, gbase | (j + 1));
            int s2 = __shfl(ids16, gbase | (j + 2));
            int s3 = __shfl(ids16, gbase | (j + 3));
            uint2 u0 = *(const uint2*)(p + s0 * 64 + t * 4);
            uint2 u1 = *(const uint2*)(p + s1 * 64 + t * 4);
            uint2 u2 = *(const uint2*)(p + s2 * 64 + t * 4);
            uint2 u3 = *(const uint2*)(p + s3 * 64 + t * 4);
            a0 += bflo(u0.x) + bflo(u1.x) + bflo(u2.x) + bflo(u3.x);
            a1 += bfhi(u0.x) + bfhi(u1.x) + bfhi(u2.x) + bfhi(u3.x);
            a2 += bflo(u0.y) + bflo(u1.y) + bflo(u2.y) + bflo(u3.y);
            a3 += bfhi(u0.y) + bfhi(u1.y) + bfhi(u2.y) + bfhi(u3.y);
        }
        for (; j < lim; ++j) {
            int s = __shfl(ids16, gbase | j);
            uint2 u = *(const uint2*)(p + s * 64 + t * 4);
            a0 += bflo(u.x);
            a1 += bfhi(u.x);
            a2 += bflo(u.y);
            a3 += bfhi(u.y);
        }
    }
    // inline layer-2 overflow additions (n is ~always 0)
    int n = *ovfc;
    if (n > OVF_CAP) n = OVF_CAP;
    for (int idx = 0; idx < n; ++idx) {
        if (ovf[idx * 2 + 1] == node) {
            int s = ovf[idx * 2];
            uint2 u = *(const uint2*)(p + s * 64 + t * 4);
            a0 += bflo(u.x);
            a1 += bfhi(u.x);
            a2 += bflo(u.y);
            a3 += bfhi(u.y);
        }
    }
    float inv = 1.0f / fmaxf((float)deg, 1.0f);
    float4 qv = *(const float4*)&q[node * 64 + t * 4];
    *(float4*)&out[node * 64 + t * 4] =
        make_float4(a0 * inv + qv.x, a1 * inv + qv.y,
                    a2 * inv + qv.z, a3 * inv + qv.w);
}

extern "C" void kernel_launch(void* const* d_in, const int* in_sizes, int n_in,
                              void* d_out, int out_size, void* d_ws, size_t ws_size,
                              hipStream_t stream) {
    const float* x   = (const float*)d_in[0];
    const float* W1l = (const float*)d_in[1];
    const float* W1r = (const float*)d_in[2];
    const float* b1  = (const float*)d_in[3];
    const float* W2l = (const float*)d_in[4];
    const float* W2r = (const float*)d_in[5];
    const float* b2  = (const float*)d_in[6];
    const int*   ei  = (const int*)d_in[7];

    int*   wsi      = (int*)d_ws;
    float* wsf      = (float*)d_ws;
    int*   counts   = wsi;
    int*   ovfc     = wsi + 100352;
    int*   spillc   = wsi + 100353;
    int*   gcur     = wsi + 100416;
    int*   ovf      = wsi + 100928;
    int2*  spill    = (int2*)(wsi + 109120);
    short* Bf1      = (short*)(wsi + 117312);
    short* Bf2      = (short*)(wsi + 133696);
    int*   slots    = wsi + 150080;
    unsigned* rec   = (unsigned*)(wsi + 6572608);
    unsigned short* xh = (unsigned short*)(wsi + 8178240);
    unsigned short* p_bf = (unsigned short*)(wsi + 20978240);
    float* q        = wsf + 24178240;
    float* out      = (float*)d_out;

    prep_kernel<<<(N_NODES * 16 + 255) / 256, 256, 0, stream>>>(
        (const float4*)x, (ushort4*)xh, W1l, W1r, W2l, W2r,
        Bf1, Bf2, (int4*)gcur, ovfc, spillc);

    // indexing: LDS-binned two-pass (spill handled inside build)
    bin_kernel<<<(N_EDGES + BIN_CHUNK - 1) / BIN_CHUNK, 256, 0, stream>>>(
        ei, rec, gcur, spillc, spill);
    build_kernel<<<NBKT, 256, 0, stream>>>(
        rec, gcur, spill, spillc, counts, slots, ovfc, ovf);

    // fused gather + MLP: means (LDS) -> h (LDS) -> p_bf, q
    mlp_fused_kernel<<<(N_NODES + 127) / 128, 256, 0, stream>>>(
        xh, x, counts, slots, Bf1, b1, Bf2, b2, ovf, ovfc, p_bf, q);

    // fused layer-2 aggregation + epilogue (ovf additions inside)
    gather_final_kernel<<<(N_NODES + 15) / 16, 256, 0, stream>>>(
        p_bf, counts, slots, q, ovf, ovfc, out);
}